// Round 15
// baseline (1471.614 us; speedup 1.0000x reference)
//
#include <hip/hip_runtime.h>
#include <hip/hip_bf16.h>

#define HD 128
#define RD 64
#define H3 384

typedef float f32x4 __attribute__((ext_vector_type(4)));
typedef unsigned short us8 __attribute__((ext_vector_type(8)));
typedef __bf16 bf16x8 __attribute__((ext_vector_type(8)));

__device__ __forceinline__ float silu_f(float x) {
    return x / (1.0f + __expf(-x));
}
__device__ __forceinline__ unsigned short f2bf(float x) {
    __hip_bfloat16 h = __float2bfloat16(x);
    return *reinterpret_cast<unsigned short*>(&h);
}
__device__ __forceinline__ float bf2f(unsigned short u) {
    return __uint_as_float(((unsigned)u) << 16);
}
// 3-term split-precision MFMA bundle: (Ah+Al)@(Bh+Bl) ~= AhBh + AhBl + AlBh
__device__ __forceinline__ f32x4 mfma3(us8 ah, us8 al, us8 bh, us8 bl, f32x4 c) {
    bf16x8 AH = __builtin_bit_cast(bf16x8, ah);
    bf16x8 AL = __builtin_bit_cast(bf16x8, al);
    bf16x8 BH = __builtin_bit_cast(bf16x8, bh);
    bf16x8 BL = __builtin_bit_cast(bf16x8, bl);
    c = __builtin_amdgcn_mfma_f32_16x16x32_bf16(AH, BH, c, 0, 0, 0);
    c = __builtin_amdgcn_mfma_f32_16x16x32_bf16(AH, BL, c, 0, 0, 0);
    c = __builtin_amdgcn_mfma_f32_16x16x32_bf16(AL, BH, c, 0, 0, 0);
    return c;
}
// 2-term: A(bf16) @ (Bh+Bl)
__device__ __forceinline__ f32x4 mfma2(us8 ah, us8 bh, us8 bl, f32x4 c) {
    bf16x8 AH = __builtin_bit_cast(bf16x8, ah);
    bf16x8 BH = __builtin_bit_cast(bf16x8, bh);
    bf16x8 BL = __builtin_bit_cast(bf16x8, bl);
    c = __builtin_amdgcn_mfma_f32_16x16x32_bf16(AH, BH, c, 0, 0, 0);
    c = __builtin_amdgcn_mfma_f32_16x16x32_bf16(AH, BL, c, 0, 0, 0);
    return c;
}

// transpose + split f32 weights [K][OUT] -> bf16 hi/lo [OUT][K], nlay layers
__global__ void wprep_kernel(const float* __restrict__ src,
                             unsigned short* __restrict__ dhi, unsigned short* __restrict__ dlo,
                             int K, int OUT, int sStride, int dStride, int nlay) {
    int total = K * OUT;
    for (int idx = blockIdx.x * blockDim.x + threadIdx.x; idx < total * nlay;
         idx += gridDim.x * blockDim.x) {
        int lyr = idx / total, r = idx % total;
        int o = r / K, k = r % K;
        float x = src[(size_t)lyr * sStride + (size_t)k * OUT + o];
        unsigned short hi = f2bf(x);
        unsigned short lo = f2bf(x - bf2f(hi));
        dhi[(size_t)lyr * dStride + (size_t)o * K + k] = hi;
        dlo[(size_t)lyr * dStride + (size_t)o * K + k] = lo;
    }
}

// condG[g,h] = z[g]@z_w + z_b + t_emb[g]@t_w + t_b
__global__ __launch_bounds__(128) void cond_kernel(const float* __restrict__ z, const float* __restrict__ t,
                            const float* __restrict__ z_w, const float* __restrict__ z_b,
                            const float* __restrict__ t_w, const float* __restrict__ t_b,
                            float* __restrict__ condG) {
    int g = blockIdx.x;
    int k = threadIdx.x;
    __shared__ float zr[128];
    __shared__ float te[64];
    zr[k] = z[g * 128 + k];
    if (k < 32) {
        float f = __expf(-9.2103403719761836f * (float)k / 31.0f);
        float e = t[g] * f;
        te[k] = sinf(e);
        te[32 + k] = cosf(e);
    }
    __syncthreads();
    float acc = z_b[k] + t_b[k];
    #pragma unroll 8
    for (int i = 0; i < 128; ++i) acc += zr[i] * z_w[i * 128 + k];
    #pragma unroll 8
    for (int i = 0; i < 64; ++i) acc += te[i] * t_w[i * 128 + k];
    condG[g * 128 + k] = acc;
}

// s[n,h] = atom_embed[types[n], h] + condG[batch[n], h]
__global__ void init_kernel(const int* __restrict__ types, const float* __restrict__ emb,
                            const float* __restrict__ condG, const int* __restrict__ batch,
                            float* __restrict__ s, int N_) {
    int i = blockIdx.x * blockDim.x + threadIdx.x;
    if (i < N_ * HD) {
        int n = i >> 7;
        int k = i & 127;
        s[i] = emb[types[n] * HD + k] + condG[batch[n] * 128 + k];
    }
}

__global__ void geom_kernel(const float* __restrict__ coords, const int* __restrict__ srcI,
                            const int* __restrict__ dstI, const int* __restrict__ batch,
                            const float* __restrict__ lattice, const float* __restrict__ offs,
                            float* __restrict__ dist, float* __restrict__ unit, int E_) {
    int e = blockIdx.x * blockDim.x + threadIdx.x;
    if (e >= E_) return;
    int sn = srcI[e], dn = dstI[e];
    float f0 = coords[dn * 3 + 0] - coords[sn * 3 + 0] + offs[e * 3 + 0];
    float f1 = coords[dn * 3 + 1] - coords[sn * 3 + 1] + offs[e * 3 + 1];
    float f2 = coords[dn * 3 + 2] - coords[sn * 3 + 2] + offs[e * 3 + 2];
    const float* Lg = lattice + batch[sn] * 9;
    float c0 = f0 * Lg[0] + f1 * Lg[3] + f2 * Lg[6];
    float c1 = f0 * Lg[1] + f1 * Lg[4] + f2 * Lg[7];
    float c2 = f0 * Lg[2] + f1 * Lg[5] + f2 * Lg[8];
    float nrm = sqrtf(c0 * c0 + c1 * c1 + c2 * c2);
    dist[e] = fmaxf(nrm, 1e-8f);
    float inv = 1.0f / fmaxf(nrm, 1e-12f);
    unit[e * 3 + 0] = c0 * inv;
    unit[e * 3 + 1] = c1 * inv;
    unit[e * 3 + 2] = c2 * inv;
}

__global__ void hist_kernel(const int* __restrict__ dstI, int* __restrict__ cnt, int E_) {
    int e = blockIdx.x * blockDim.x + threadIdx.x;
    if (e < E_) atomicAdd(&cnt[dstI[e]], 1);
}

__global__ __launch_bounds__(1024) void scan_kernel(const int* __restrict__ cnt, int* __restrict__ cur, int n) {
    __shared__ int tmp[1024];
    __shared__ int carry_s;
    if (threadIdx.x == 0) carry_s = 0;
    __syncthreads();
    for (int base = 0; base < n; base += 1024) {
        int i = base + threadIdx.x;
        int x = (i < n) ? cnt[i] : 0;
        tmp[threadIdx.x] = x;
        __syncthreads();
        for (int off = 1; off < 1024; off <<= 1) {
            int y = (threadIdx.x >= off) ? tmp[threadIdx.x - off] : 0;
            __syncthreads();
            tmp[threadIdx.x] += y;
            __syncthreads();
        }
        if (i < n) cur[i] = carry_s + tmp[threadIdx.x] - x;
        __syncthreads();
        if (threadIdx.x == 0) carry_s += tmp[1023];
        __syncthreads();
    }
}

// scatter edges into dst-sorted order; unit packed as float4 (ux,uy,uz,dist)
__global__ void scatter_kernel(const int* __restrict__ srcI, const int* __restrict__ dstI,
                               const float* __restrict__ dist, const float* __restrict__ unit,
                               int* __restrict__ cur,
                               float* __restrict__ dist_s, float4* __restrict__ unit4_s,
                               int* __restrict__ src_s, int* __restrict__ dst_s, int E_) {
    int e = blockIdx.x * blockDim.x + threadIdx.x;
    if (e >= E_) return;
    int d = dstI[e];
    int p = atomicAdd(&cur[d], 1);
    float dd = dist[e];
    dist_s[p] = dd;
    unit4_s[p] = make_float4(unit[e * 3 + 0], unit[e * 3 + 1], unit[e * 3 + 2], dd);
    src_s[p] = srcI[e];
    dst_s[p] = d;
}

// ---- MFMA phi: phi = silu(s@w1+b1)@w2+b2, 32 nodes/block, 256 threads ----
#define PSA 136
__global__ __launch_bounds__(256, 2) void phi_mfma(
    const float* __restrict__ s,
    const unsigned short* __restrict__ w1h, const unsigned short* __restrict__ w1l,
    const float* __restrict__ b1,
    const unsigned short* __restrict__ w2h, const unsigned short* __restrict__ w2l,
    const float* __restrict__ b2,
    float* __restrict__ phi, int N_) {
    __shared__ unsigned short Ah[32 * PSA], Al[32 * PSA], Hh[32 * PSA], Hl[32 * PSA];
    const int tid = threadIdx.x;
    const int n0 = blockIdx.x * 32;
    for (int idx = tid; idx < 32 * 128; idx += 256) {
        int j = idx >> 7, k = idx & 127;
        int n = n0 + j; if (n >= N_) n = N_ - 1;
        float x = s[(size_t)n * 128 + k];
        unsigned short h = f2bf(x);
        Ah[j * PSA + k] = h;
        Al[j * PSA + k] = f2bf(x - bf2f(h));
    }
    __syncthreads();
    const int w = tid >> 6, l = tid & 63;
    const int lr = l & 15, lk = (l >> 4) << 3, rg0 = (l >> 4) << 2;
    const f32x4 zero4 = {0.0f, 0.0f, 0.0f, 0.0f};
    f32x4 acc1[2][2];
    #pragma unroll
    for (int rt = 0; rt < 2; ++rt)
        #pragma unroll
        for (int ci = 0; ci < 2; ++ci) acc1[rt][ci] = zero4;
    #pragma unroll
    for (int kt = 0; kt < 4; ++kt) {
        int kk = kt * 32 + lk;
        us8 bh[2], bl[2], ah[2], alo[2];
        #pragma unroll
        for (int ci = 0; ci < 2; ++ci) {
            int col = (w * 2 + ci) * 16 + lr;
            bh[ci] = *(const us8*)(w1h + (size_t)col * 128 + kk);
            bl[ci] = *(const us8*)(w1l + (size_t)col * 128 + kk);
        }
        #pragma unroll
        for (int rt = 0; rt < 2; ++rt) {
            ah[rt]  = *(const us8*)(Ah + (rt * 16 + lr) * PSA + kk);
            alo[rt] = *(const us8*)(Al + (rt * 16 + lr) * PSA + kk);
        }
        #pragma unroll
        for (int rt = 0; rt < 2; ++rt)
            #pragma unroll
            for (int ci = 0; ci < 2; ++ci)
                acc1[rt][ci] = mfma3(ah[rt], alo[rt], bh[ci], bl[ci], acc1[rt][ci]);
    }
    #pragma unroll
    for (int rt = 0; rt < 2; ++rt)
        #pragma unroll
        for (int ci = 0; ci < 2; ++ci) {
            int col = (w * 2 + ci) * 16 + lr;
            float bb = b1[col];
            #pragma unroll
            for (int rg = 0; rg < 4; ++rg) {
                int j = rt * 16 + rg0 + rg;
                float hv = silu_f(acc1[rt][ci][rg] + bb);
                unsigned short hh = f2bf(hv);
                Hh[j * PSA + col] = hh;
                Hl[j * PSA + col] = f2bf(hv - bf2f(hh));
            }
        }
    __syncthreads();
    f32x4 acc2[2][6];
    #pragma unroll
    for (int rt = 0; rt < 2; ++rt)
        #pragma unroll
        for (int ci = 0; ci < 6; ++ci) acc2[rt][ci] = zero4;
    #pragma unroll
    for (int kt = 0; kt < 4; ++kt) {
        int kk = kt * 32 + lk;
        us8 ah[2], alo[2];
        #pragma unroll
        for (int rt = 0; rt < 2; ++rt) {
            ah[rt]  = *(const us8*)(Hh + (rt * 16 + lr) * PSA + kk);
            alo[rt] = *(const us8*)(Hl + (rt * 16 + lr) * PSA + kk);
        }
        #pragma unroll
        for (int ci = 0; ci < 6; ++ci) {
            int col = (w * 6 + ci) * 16 + lr;
            us8 bh = *(const us8*)(w2h + (size_t)col * 128 + kk);
            us8 bl = *(const us8*)(w2l + (size_t)col * 128 + kk);
            #pragma unroll
            for (int rt = 0; rt < 2; ++rt)
                acc2[rt][ci] = mfma3(ah[rt], alo[rt], bh, bl, acc2[rt][ci]);
        }
    }
    #pragma unroll
    for (int rt = 0; rt < 2; ++rt)
        #pragma unroll
        for (int ci = 0; ci < 6; ++ci) {
            int col = (w * 6 + ci) * 16 + lr;
            float bb = b2[col];
            #pragma unroll
            for (int rg = 0; rg < 4; ++rg) {
                int j = rt * 16 + rg0 + rg;
                int n = n0 + j;
                if (n < N_) phi[(size_t)n * 384 + col] = acc2[rt][ci][rg] + bb;
            }
        }
}

// ---- MFMA update: 16 nodes/block, 256 threads.  Epilogue also zeroes dv for next layer. ----
__global__ __launch_bounds__(256, 2) void upd_mfma(
    const unsigned short* __restrict__ Uh, const unsigned short* __restrict__ Ul,
    const unsigned short* __restrict__ Vh, const unsigned short* __restrict__ Vl,
    const unsigned short* __restrict__ w1h, const unsigned short* __restrict__ w1l,
    const float* __restrict__ b1,
    const unsigned short* __restrict__ w2h, const unsigned short* __restrict__ w2l,
    const float* __restrict__ b2,
    float* __restrict__ s, float* __restrict__ v, float* __restrict__ dv,
    const float* __restrict__ condG, const int* __restrict__ batch, int addcond, int N_) {
    __shared__ unsigned short SMA[2 * 48 * 136];
    __shared__ float UvL[48 * 132];
    __shared__ float VvL[48 * 132];
    unsigned short* VNh = SMA;
    unsigned short* VNl = SMA + 48 * 136;
    unsigned short* A1h = SMA;
    unsigned short* A1l = SMA + 16 * 264;
    unsigned short* a1h = SMA + 32 * 264;
    unsigned short* a1l = SMA + 32 * 264 + 16 * 136;
    float* o384 = VvL;
    const int tid = threadIdx.x;
    const int n0 = blockIdx.x * 16;
    for (int idx = tid; idx < 48 * 128; idx += 256) {
        int r = idx >> 7, k = idx & 127;
        int c = r >> 4, j = r & 15;
        int n = n0 + j; if (n >= N_) n = N_ - 1;
        size_t off = (size_t)n * 384 + c * 128 + k;
        float x = v[off] + dv[off];
        unsigned short h = f2bf(x);
        VNh[r * 136 + k] = h;
        VNl[r * 136 + k] = f2bf(x - bf2f(h));
    }
    __syncthreads();
    const int w = tid >> 6, l = tid & 63;
    const int lr = l & 15, lk = (l >> 4) << 3, rg0 = (l >> 4) << 2;
    const f32x4 zero4 = {0.0f, 0.0f, 0.0f, 0.0f};
    {
        f32x4 acc[3][2];
        #pragma unroll
        for (int rt = 0; rt < 3; ++rt) { acc[rt][0] = zero4; acc[rt][1] = zero4; }
        #pragma unroll
        for (int kt = 0; kt < 4; ++kt) {
            int kk = kt * 32 + lk;
            us8 bh[2], bl[2];
            #pragma unroll
            for (int ci = 0; ci < 2; ++ci) {
                int col = (w * 2 + ci) * 16 + lr;
                bh[ci] = *(const us8*)(Uh + (size_t)col * 128 + kk);
                bl[ci] = *(const us8*)(Ul + (size_t)col * 128 + kk);
            }
            #pragma unroll
            for (int rt = 0; rt < 3; ++rt) {
                us8 ah  = *(const us8*)(VNh + (rt * 16 + lr) * 136 + kk);
                us8 alo = *(const us8*)(VNl + (rt * 16 + lr) * 136 + kk);
                #pragma unroll
                for (int ci = 0; ci < 2; ++ci)
                    acc[rt][ci] = mfma3(ah, alo, bh[ci], bl[ci], acc[rt][ci]);
            }
        }
        #pragma unroll
        for (int rt = 0; rt < 3; ++rt)
            #pragma unroll
            for (int ci = 0; ci < 2; ++ci) {
                int col = (w * 2 + ci) * 16 + lr;
                #pragma unroll
                for (int rg = 0; rg < 4; ++rg)
                    UvL[(rt * 16 + rg0 + rg) * 132 + col] = acc[rt][ci][rg];
            }
        #pragma unroll
        for (int rt = 0; rt < 3; ++rt) { acc[rt][0] = zero4; acc[rt][1] = zero4; }
        #pragma unroll
        for (int kt = 0; kt < 4; ++kt) {
            int kk = kt * 32 + lk;
            us8 bh[2], bl[2];
            #pragma unroll
            for (int ci = 0; ci < 2; ++ci) {
                int col = (w * 2 + ci) * 16 + lr;
                bh[ci] = *(const us8*)(Vh + (size_t)col * 128 + kk);
                bl[ci] = *(const us8*)(Vl + (size_t)col * 128 + kk);
            }
            #pragma unroll
            for (int rt = 0; rt < 3; ++rt) {
                us8 ah  = *(const us8*)(VNh + (rt * 16 + lr) * 136 + kk);
                us8 alo = *(const us8*)(VNl + (rt * 16 + lr) * 136 + kk);
                #pragma unroll
                for (int ci = 0; ci < 2; ++ci)
                    acc[rt][ci] = mfma3(ah, alo, bh[ci], bl[ci], acc[rt][ci]);
            }
        }
        #pragma unroll
        for (int rt = 0; rt < 3; ++rt)
            #pragma unroll
            for (int ci = 0; ci < 2; ++ci) {
                int col = (w * 2 + ci) * 16 + lr;
                #pragma unroll
                for (int rg = 0; rg < 4; ++rg)
                    VvL[(rt * 16 + rg0 + rg) * 132 + col] = acc[rt][ci][rg];
            }
    }
    __syncthreads();
    float dotr[8];
    {
        int k = tid & 127;
        int jb = (tid >> 7) * 8;
        #pragma unroll
        for (int i = 0; i < 8; ++i) {
            int j = jb + i;
            float uv0 = UvL[j * 132 + k], uv1 = UvL[(16 + j) * 132 + k], uv2 = UvL[(32 + j) * 132 + k];
            float vv0 = VvL[j * 132 + k], vv1 = VvL[(16 + j) * 132 + k], vv2 = VvL[(32 + j) * 132 + k];
            dotr[i] = uv0 * vv0 + uv1 * vv1 + uv2 * vv2;
            float vnv = sqrtf(vv0 * vv0 + vv1 * vv1 + vv2 * vv2 + 1e-8f);
            int n = n0 + j; if (n >= N_) n = N_ - 1;
            float sv = s[(size_t)n * 128 + k];
            unsigned short h1 = f2bf(sv);
            A1h[j * 264 + k] = h1;
            A1l[j * 264 + k] = f2bf(sv - bf2f(h1));
            unsigned short h2 = f2bf(vnv);
            A1h[j * 264 + 128 + k] = h2;
            A1l[j * 264 + 128 + k] = f2bf(vnv - bf2f(h2));
        }
    }
    __syncthreads();
    {
        f32x4 acc[2]; acc[0] = zero4; acc[1] = zero4;
        #pragma unroll
        for (int kt = 0; kt < 8; ++kt) {
            int kk = kt * 32 + lk;
            us8 ah  = *(const us8*)(A1h + lr * 264 + kk);
            us8 alo = *(const us8*)(A1l + lr * 264 + kk);
            #pragma unroll
            for (int ci = 0; ci < 2; ++ci) {
                int col = (w * 2 + ci) * 16 + lr;
                us8 bh = *(const us8*)(w1h + (size_t)col * 256 + kk);
                us8 bl = *(const us8*)(w1l + (size_t)col * 256 + kk);
                acc[ci] = mfma3(ah, alo, bh, bl, acc[ci]);
            }
        }
        #pragma unroll
        for (int ci = 0; ci < 2; ++ci) {
            int col = (w * 2 + ci) * 16 + lr;
            float bb = b1[col];
            #pragma unroll
            for (int rg = 0; rg < 4; ++rg) {
                int j = rg0 + rg;
                float hv = silu_f(acc[ci][rg] + bb);
                unsigned short hh = f2bf(hv);
                a1h[j * 136 + col] = hh;
                a1l[j * 136 + col] = f2bf(hv - bf2f(hh));
            }
        }
    }
    __syncthreads();
    {
        f32x4 acc[6];
        #pragma unroll
        for (int ci = 0; ci < 6; ++ci) acc[ci] = zero4;
        #pragma unroll
        for (int kt = 0; kt < 4; ++kt) {
            int kk = kt * 32 + lk;
            us8 ah  = *(const us8*)(a1h + lr * 136 + kk);
            us8 alo = *(const us8*)(a1l + lr * 136 + kk);
            #pragma unroll
            for (int ci = 0; ci < 6; ++ci) {
                int col = (w * 6 + ci) * 16 + lr;
                us8 bh = *(const us8*)(w2h + (size_t)col * 128 + kk);
                us8 bl = *(const us8*)(w2l + (size_t)col * 128 + kk);
                acc[ci] = mfma3(ah, alo, bh, bl, acc[ci]);
            }
        }
        #pragma unroll
        for (int ci = 0; ci < 6; ++ci) {
            int col = (w * 6 + ci) * 16 + lr;
            float bb = b2[col];
            #pragma unroll
            for (int rg = 0; rg < 4; ++rg) {
                int j = rg0 + rg;
                o384[j * 388 + col] = acc[ci][rg] + bb;
            }
        }
    }
    __syncthreads();
    {
        int k = tid & 127;
        int jb = (tid >> 7) * 8;
        #pragma unroll
        for (int i = 0; i < 8; ++i) {
            int j = jb + i;
            int n = n0 + j;
            if (n >= N_) continue;
            float a0  = o384[j * 388 + k];
            float aH  = o384[j * 388 + 128 + k];
            float a2v = o384[j * 388 + 256 + k];
            #pragma unroll
            for (int c = 0; c < 3; ++c) {
                size_t off = (size_t)n * 384 + c * 128 + k;
                float dvv = dv[off];
                v[off] = v[off] + dvv + a0 * UvL[(c * 16 + j) * 132 + k];
                dv[off] = 0.0f;   // zero for next layer's edge accumulation
            }
            float cadd = addcond ? condG[(size_t)batch[n] * 128 + k] : 0.0f;
            s[(size_t)n * 128 + k] += aH * dotr[i] + a2v + cadd;
        }
    }
}

// ---- MFMA edge v9: 8-deep gather prefetch (4 serial hops), LDS metadata, f32 filt ----
// 64 sorted edges/block, 256 threads. LDS ~34.8KB -> 4 blocks/CU.
#define EB 64
#define NXCD 8
__global__ __launch_bounds__(256, 4) void edge_mfma(
    const float* __restrict__ phi, const float* __restrict__ v,
    const float* __restrict__ dist_s, const float4* __restrict__ unit4_s,
    const int* __restrict__ src_s, const int* __restrict__ dst_s,
    const unsigned short* __restrict__ rwh, const unsigned short* __restrict__ rwl,  // [384][64]
    const float* __restrict__ rb,
    float* __restrict__ s, float* __restrict__ dv, int E_, int skipv) {
    __shared__ unsigned short Rh[4096];   // 8192 B  (A frags bf16, persistent)
    __shared__ float filt[16 * 388];      // 24832 B (f32, per-chunk)
    __shared__ int   mSrc[64];            // 256 B
    __shared__ int   mDst[64];            // 256 B
    __shared__ float4 mU4[64];            // 1024 B
    // bijective XCD swizzle (m204)
    int nwg = gridDim.x;
    int q = nwg / NXCD, r = nwg % NXCD;
    int xcd = blockIdx.x % NXCD, bidx = blockIdx.x / NXCD;
    int bid = (xcd < r ? xcd * (q + 1) : r * (q + 1) + (xcd - r) * q) + bidx;
    const int tid = threadIdx.x;
    const int e0 = bid * EB;
    // phase 0: stage the block's 64-edge metadata in LDS (coalesced)
    if (tid < 64) {
        int ec = e0 + tid; if (ec >= E_) ec = E_ - 1;
        mSrc[tid] = src_s[ec];
        mDst[tid] = dst_s[ec];
        mU4[tid]  = unit4_s[ec];
    }
    // phase 1: rbf (bf16) in MFMA A-fragment order:
    // idx = ((kt*4 + mt)*64 + lane)*8 + i -> edge = mt*16+(lane&15), r = kt*32+(lane>>4)*8+i
    #pragma unroll
    for (int it = 0; it < 16; ++it) {
        int idx2 = it * 256 + tid;
        int i = idx2 & 7;
        int l2 = (idx2 >> 3) & 63;
        int mt = (idx2 >> 9) & 3;
        int kt = idx2 >> 11;
        int edge = mt * 16 + (l2 & 15);
        int rr = kt * 32 + ((l2 >> 4) << 3) + i;
        float val = 0.0f;
        int ge = e0 + edge;
        if (ge < E_) {
            float d = dist_s[ge];
            float c = 6.0f * (float)rr / 63.0f;
            float tt = d - c;
            val = __expf(-(64.0f / 6.0f) * tt * tt);
        }
        Rh[idx2] = f2bf(val);
    }
    const int w = tid >> 6, l = tid & 63;
    const int lr = l & 15, rg0 = (l >> 4) << 2;
    const int sub = tid >> 7;        // 0..1
    const int col = tid & 127;
    float bias[6];
    #pragma unroll
    for (int nt = 0; nt < 6; ++nt) bias[nt] = rb[w * 96 + nt * 16 + lr];
    const f32x4 zero4 = {0.0f, 0.0f, 0.0f, 0.0f};
    float as = 0.0f, ad0 = 0.0f, ad1 = 0.0f, ad2 = 0.0f;
    int rd = -1;
    __syncthreads();   // Rh + meta ready
    #pragma unroll
    for (int ch = 0; ch < 4; ++ch) {
        // MFMA for this 16-edge chunk (acc = 24 VGPRs)
        f32x4 acc[6];
        #pragma unroll
        for (int nt = 0; nt < 6; ++nt) acc[nt] = zero4;
        #pragma unroll
        for (int kt = 0; kt < 2; ++kt) {
            int base = ((kt * 4 + ch) * 64 + l) * 8;
            us8 ah = *(const us8*)(Rh + base);
            int kk = kt * 32 + ((l >> 4) << 3);
            #pragma unroll
            for (int nt = 0; nt < 6; ++nt) {
                int c2 = w * 96 + nt * 16 + lr;
                us8 bh = *(const us8*)(rwh + (size_t)c2 * 64 + kk);
                us8 bl = *(const us8*)(rwl + (size_t)c2 * 64 + kk);
                acc[nt] = mfma2(ah, bh, bl, acc[nt]);
            }
        }
        __syncthreads();   // previous chunk's filt fully consumed
        #pragma unroll
        for (int nt = 0; nt < 6; ++nt) {
            int c2 = w * 96 + nt * 16 + lr;
            #pragma unroll
            for (int rg = 0; rg < 4; ++rg)
                filt[(rg0 + rg) * 388 + c2] = acc[nt][rg] + bias[nt];
        }
        __syncthreads();
        // consume: single 8-deep prefetched group per sub
        int lb = ch * 16 + sub * 8;     // local edge base within block (0..63)
        int sn8[8], dn8[8];
        #pragma unroll
        for (int i = 0; i < 8; ++i) {
            sn8[i] = mSrc[lb + i];
            dn8[i] = mDst[lb + i];
        }
        float P0[8], P1[8], P2[8], V0[8], V1[8], V2[8];
        #pragma unroll
        for (int i = 0; i < 8; ++i) {
            const float* phr = phi + (size_t)sn8[i] * 384;
            P0[i] = phr[col];
            P1[i] = phr[128 + col];
            P2[i] = phr[256 + col];
        }
        if (!skipv) {
            #pragma unroll
            for (int i = 0; i < 8; ++i) {
                const float* vr = v + (size_t)sn8[i] * 384;
                V0[i] = vr[col];
                V1[i] = vr[128 + col];
                V2[i] = vr[256 + col];
            }
        } else {
            #pragma unroll
            for (int i = 0; i < 8; ++i) { V0[i] = 0.0f; V1[i] = 0.0f; V2[i] = 0.0f; }
        }
        #pragma unroll
        for (int i = 0; i < 8; ++i) {
            int e = e0 + lb + i;
            if (e >= E_) break;
            int dn = dn8[i];
            if (dn != rd) {   // wave-uniform within sub
                if (rd >= 0) {
                    atomicAdd(&s[(size_t)rd * 128 + col], as);
                    atomicAdd(&dv[(size_t)rd * 384 + col], ad0);
                    atomicAdd(&dv[(size_t)rd * 384 + 128 + col], ad1);
                    atomicAdd(&dv[(size_t)rd * 384 + 256 + col], ad2);
                }
                as = ad0 = ad1 = ad2 = 0.0f;
                rd = dn;
            }
            int fr = sub * 8 + i;
            float f0 = filt[fr * 388 + col];
            float f1 = filt[fr * 388 + 128 + col];
            float f2v = filt[fr * 388 + 256 + col];
            float x0 = P0[i] * f0;
            float x1 = P1[i] * f1;
            float x2 = P2[i] * f2v;
            float4 u = mU4[lb + i];
            as += x0;
            ad0 += x1 * V0[i] + x2 * u.x;
            ad1 += x1 * V1[i] + x2 * u.y;
            ad2 += x1 * V2[i] + x2 * u.z;
        }
    }
    if (rd >= 0) {
        atomicAdd(&s[(size_t)rd * 128 + col], as);
        atomicAdd(&dv[(size_t)rd * 384 + col], ad0);
        atomicAdd(&dv[(size_t)rd * 384 + 128 + col], ad1);
        atomicAdd(&dv[(size_t)rd * 384 + 256 + col], ad2);
    }
}

// output heads: 8 nodes per block
#define HPB 8
__global__ __launch_bounds__(128, 4) void heads_kernel(
    const float* __restrict__ s,
    const float* __restrict__ hc_w1, const float* __restrict__ hc_b1,
    const float* __restrict__ hc_w2, const float* __restrict__ hc_b2,
    const float* __restrict__ ht_w1, const float* __restrict__ ht_b1,
    const float* __restrict__ ht_w2, const float* __restrict__ ht_b2,
    float* __restrict__ outc, float* __restrict__ outt, int N_) {
    int n0 = blockIdx.x * HPB;
    int k = threadIdx.x;
    __shared__ float sr[HPB][128];
    __shared__ float h1[HPB][128];
    __shared__ float h2[HPB][128];
    #pragma unroll
    for (int j = 0; j < HPB; ++j) {
        int n = n0 + j;
        sr[j][k] = (n < N_) ? s[(size_t)n * 128 + k] : 0.0f;
    }
    __syncthreads();
    float a[HPB], b[HPB];
    #pragma unroll
    for (int j = 0; j < HPB; ++j) { a[j] = hc_b1[k]; b[j] = ht_b1[k]; }
    for (int h = 0; h < 128; h += 4) {
        float wa0 = hc_w1[h * 128 + k],       wa1 = hc_w1[(h + 1) * 128 + k];
        float wa2 = hc_w1[(h + 2) * 128 + k], wa3 = hc_w1[(h + 3) * 128 + k];
        float wb0 = ht_w1[h * 128 + k],       wb1 = ht_w1[(h + 1) * 128 + k];
        float wb2 = ht_w1[(h + 2) * 128 + k], wb3 = ht_w1[(h + 3) * 128 + k];
        #pragma unroll
        for (int j = 0; j < HPB; ++j) {
            const float4 x = *reinterpret_cast<const float4*>(&sr[j][h]);
            a[j] = fmaf(x.w, wa3, fmaf(x.z, wa2, fmaf(x.y, wa1, fmaf(x.x, wa0, a[j]))));
            b[j] = fmaf(x.w, wb3, fmaf(x.z, wb2, fmaf(x.y, wb1, fmaf(x.x, wb0, b[j]))));
        }
    }
    #pragma unroll
    for (int j = 0; j < HPB; ++j) {
        h1[j][k] = silu_f(a[j]);
        h2[j][k] = silu_f(b[j]);
    }
    __syncthreads();
    if (k < 101) {
        for (int j = 0; j < HPB; ++j) {
            int n = n0 + j;
            if (n >= N_) break;
            float c = ht_b2[k];
            #pragma unroll 4
            for (int h = 0; h < 128; ++h) c += h2[j][h] * ht_w2[h * 101 + k];
            outt[(size_t)n * 101 + k] = c;
        }
    }
    if (k < 3) {
        for (int j = 0; j < HPB; ++j) {
            int n = n0 + j;
            if (n >= N_) break;
            float c = hc_b2[k];
            #pragma unroll 4
            for (int h = 0; h < 128; ++h) c += h1[j][h] * hc_w2[h * 3 + k];
            outc[(size_t)n * 3 + k] = c;
        }
    }
}

extern "C" void kernel_launch(void* const* d_in, const int* in_sizes, int n_in,
                              void* d_out, int out_size, void* d_ws, size_t ws_size,
                              hipStream_t stream) {
    const float* coords  = (const float*)d_in[0];
    const int*   types   = (const int*)d_in[1];
    const float* z       = (const float*)d_in[2];
    const float* t       = (const float*)d_in[3];
    const int*   eidx    = (const int*)d_in[4];
    const int*   batch   = (const int*)d_in[5];
    const float* lattice = (const float*)d_in[6];
    const float* offs    = (const float*)d_in[7];
    const float* aemb    = (const float*)d_in[8];
    const float* z_w     = (const float*)d_in[9];
    const float* z_b     = (const float*)d_in[10];
    const float* t_w     = (const float*)d_in[11];
    const float* t_b     = (const float*)d_in[12];
    const float* msg_w1  = (const float*)d_in[13];
    const float* msg_b1  = (const float*)d_in[14];
    const float* msg_w2  = (const float*)d_in[15];
    const float* msg_b2  = (const float*)d_in[16];
    const float* rbf_w   = (const float*)d_in[17];
    const float* rbf_b   = (const float*)d_in[18];
    const float* Um      = (const float*)d_in[19];
    const float* Vm      = (const float*)d_in[20];
    const float* upd_w1  = (const float*)d_in[21];
    const float* upd_b1  = (const float*)d_in[22];
    const float* upd_w2  = (const float*)d_in[23];
    const float* upd_b2  = (const float*)d_in[24];
    const float* hc_w1   = (const float*)d_in[25];
    const float* hc_b1   = (const float*)d_in[26];
    const float* hc_w2   = (const float*)d_in[27];
    const float* hc_b2   = (const float*)d_in[28];
    const float* ht_w1   = (const float*)d_in[29];
    const float* ht_b1   = (const float*)d_in[30];
    const float* ht_w2   = (const float*)d_in[31];
    const float* ht_b2   = (const float*)d_in[32];

    const int N = in_sizes[1];
    const int G = in_sizes[3];
    const int E = in_sizes[4] / 2;
    const int* srcI = eidx;
    const int* dstI = eidx + E;

    char* ws = (char*)d_ws;
    auto alloc = [&](size_t bytes) {
        char* p = ws;
        ws += (bytes + 255) & ~(size_t)255;
        return p;
    };
    float*  s_buf   = (float*)alloc((size_t)N * HD * 4);
    float*  v_buf   = (float*)alloc((size_t)N * H3 * 4);
    float*  dv_buf  = (float*)alloc((size_t)N * H3 * 4);
    float*  phi_buf = (float*)alloc((size_t)N * H3 * 4);
    float*  condG   = (float*)alloc((size_t)G * HD * 4);
    float*  dist_s  = (float*)alloc((size_t)E * 4);
    float4* unit4_s = (float4*)alloc((size_t)E * 16);
    int*    src_s   = (int*)alloc((size_t)E * 4);
    int*    dst_s   = (int*)alloc((size_t)E * 4);
    int*    cur     = (int*)alloc((size_t)N * 4);
    // per-layer short offsets inside wpr (layer stride LS = 409600 shorts):
    // pw1 h/l: 0/16384 ; pw2 h/l: 32768/81920 ; uw1 h/l: 131072/163840 ;
    // uw2 h/l: 196608/245760 ; U h/l: 294912/311296 ; V h/l: 327680/344064 ;
    // rw h/l: 360448/385024
    const size_t LS = 409600;
    unsigned short* wpr = (unsigned short*)alloc((size_t)4 * LS * 2);
    float* dist_t  = phi_buf;
    float* unit_t  = phi_buf + E;

    hipMemsetAsync(v_buf, 0, (size_t)N * H3 * 4, stream);
    hipMemsetAsync(dv_buf, 0, (size_t)N * H3 * 4, stream);   // layers >0 zeroed by upd_mfma
    hipMemsetAsync(cur, 0, (size_t)N * 4, stream);
    cond_kernel<<<G, 128, 0, stream>>>(z, t, z_w, z_b, t_w, t_b, condG);
    init_kernel<<<(N * HD + 255) / 256, 256, 0, stream>>>(types, aemb, condG, batch, s_buf, N);
    geom_kernel<<<(E + 255) / 256, 256, 0, stream>>>(coords, srcI, dstI, batch, lattice, offs, dist_t, unit_t, E);
    hist_kernel<<<(E + 255) / 256, 256, 0, stream>>>(dstI, cur, E);
    {
        int* cnt2 = (int*)(phi_buf + 4 * (size_t)E);
        hipMemcpyAsync(cnt2, cur, (size_t)N * 4, hipMemcpyDeviceToDevice, stream);
        scan_kernel<<<1, 1024, 0, stream>>>(cnt2, cur, N);
    }
    scatter_kernel<<<(E + 255) / 256, 256, 0, stream>>>(srcI, dstI, dist_t, unit_t, cur,
                                                        dist_s, unit4_s, src_s, dst_s, E);
    // weight prep (transpose + hi/lo split), 4 layers each
    wprep_kernel<<<256, 256, 0, stream>>>(msg_w1, wpr + 0,      wpr + 16384,  128, 128, 16384, (int)LS, 4);
    wprep_kernel<<<768, 256, 0, stream>>>(msg_w2, wpr + 32768,  wpr + 81920,  128, 384, 49152, (int)LS, 4);
    wprep_kernel<<<512, 256, 0, stream>>>(upd_w1, wpr + 131072, wpr + 163840, 256, 128, 32768, (int)LS, 4);
    wprep_kernel<<<768, 256, 0, stream>>>(upd_w2, wpr + 196608, wpr + 245760, 128, 384, 49152, (int)LS, 4);
    wprep_kernel<<<256, 256, 0, stream>>>(Um,     wpr + 294912, wpr + 311296, 128, 128, 16384, (int)LS, 4);
    wprep_kernel<<<256, 256, 0, stream>>>(Vm,     wpr + 327680, wpr + 344064, 128, 128, 16384, (int)LS, 4);
    wprep_kernel<<<384, 256, 0, stream>>>(rbf_w,  wpr + 360448, wpr + 385024, 64,  384, 24576, (int)LS, 4);

    int eblocks = (E + EB - 1) / EB;
    int pblocks = (N + 31) / 32;
    int ublocks = (N + 15) / 16;
    int hblocks = (N + HPB - 1) / HPB;
    for (int l = 0; l < 4; ++l) {
        const unsigned short* L = wpr + (size_t)l * LS;
        phi_mfma<<<pblocks, 256, 0, stream>>>(s_buf,
                L + 0, L + 16384, msg_b1 + (size_t)l * HD,
                L + 32768, L + 81920, msg_b2 + (size_t)l * H3,
                phi_buf, N);
        edge_mfma<<<eblocks, 256, 0, stream>>>(phi_buf, v_buf, dist_s, unit4_s, src_s, dst_s,
                                               L + 360448, L + 385024,
                                               rbf_b + (size_t)l * H3,
                                               s_buf, dv_buf, E, (l == 0) ? 1 : 0);
        upd_mfma<<<ublocks, 256, 0, stream>>>(
                L + 294912, L + 311296, L + 327680, L + 344064,
                L + 131072, L + 163840, upd_b1 + (size_t)l * HD,
                L + 196608, L + 245760, upd_b2 + (size_t)l * H3,
                s_buf, v_buf, dv_buf, condG, batch, (l < 3) ? 1 : 0, N);
    }
    heads_kernel<<<hblocks, 128, 0, stream>>>(s_buf, hc_w1, hc_b1, hc_w2, hc_b2,
                                        ht_w1, ht_b1, ht_w2, ht_b2,
                                        (float*)d_out, (float*)d_out + (size_t)N * 3, N);
}

// Round 16
// 1361.510 us; speedup vs baseline: 1.0809x; 1.0809x over previous
//
#include <hip/hip_runtime.h>
#include <hip/hip_bf16.h>

#define HD 128
#define RD 64
#define H3 384

typedef float f32x4 __attribute__((ext_vector_type(4)));
typedef unsigned short us8 __attribute__((ext_vector_type(8)));
typedef __bf16 bf16x8 __attribute__((ext_vector_type(8)));

__device__ __forceinline__ float silu_f(float x) {
    return x / (1.0f + __expf(-x));
}
__device__ __forceinline__ unsigned short f2bf(float x) {
    __hip_bfloat16 h = __float2bfloat16(x);
    return *reinterpret_cast<unsigned short*>(&h);
}
__device__ __forceinline__ float bf2f(unsigned short u) {
    return __uint_as_float(((unsigned)u) << 16);
}
// 3-term split-precision MFMA bundle: (Ah+Al)@(Bh+Bl) ~= AhBh + AhBl + AlBh
__device__ __forceinline__ f32x4 mfma3(us8 ah, us8 al, us8 bh, us8 bl, f32x4 c) {
    bf16x8 AH = __builtin_bit_cast(bf16x8, ah);
    bf16x8 AL = __builtin_bit_cast(bf16x8, al);
    bf16x8 BH = __builtin_bit_cast(bf16x8, bh);
    bf16x8 BL = __builtin_bit_cast(bf16x8, bl);
    c = __builtin_amdgcn_mfma_f32_16x16x32_bf16(AH, BH, c, 0, 0, 0);
    c = __builtin_amdgcn_mfma_f32_16x16x32_bf16(AH, BL, c, 0, 0, 0);
    c = __builtin_amdgcn_mfma_f32_16x16x32_bf16(AL, BH, c, 0, 0, 0);
    return c;
}
// 2-term: A(bf16) @ (Bh+Bl)
__device__ __forceinline__ f32x4 mfma2(us8 ah, us8 bh, us8 bl, f32x4 c) {
    bf16x8 AH = __builtin_bit_cast(bf16x8, ah);
    bf16x8 BH = __builtin_bit_cast(bf16x8, bh);
    bf16x8 BL = __builtin_bit_cast(bf16x8, bl);
    c = __builtin_amdgcn_mfma_f32_16x16x32_bf16(AH, BH, c, 0, 0, 0);
    c = __builtin_amdgcn_mfma_f32_16x16x32_bf16(AH, BL, c, 0, 0, 0);
    return c;
}

// transpose + split f32 weights [K][OUT] -> bf16 hi/lo [OUT][K], nlay layers
__global__ void wprep_kernel(const float* __restrict__ src,
                             unsigned short* __restrict__ dhi, unsigned short* __restrict__ dlo,
                             int K, int OUT, int sStride, int dStride, int nlay) {
    int total = K * OUT;
    for (int idx = blockIdx.x * blockDim.x + threadIdx.x; idx < total * nlay;
         idx += gridDim.x * blockDim.x) {
        int lyr = idx / total, r = idx % total;
        int o = r / K, k = r % K;
        float x = src[(size_t)lyr * sStride + (size_t)k * OUT + o];
        unsigned short hi = f2bf(x);
        unsigned short lo = f2bf(x - bf2f(hi));
        dhi[(size_t)lyr * dStride + (size_t)o * K + k] = hi;
        dlo[(size_t)lyr * dStride + (size_t)o * K + k] = lo;
    }
}

// condG[g,h] = z[g]@z_w + z_b + t_emb[g]@t_w + t_b
__global__ __launch_bounds__(128) void cond_kernel(const float* __restrict__ z, const float* __restrict__ t,
                            const float* __restrict__ z_w, const float* __restrict__ z_b,
                            const float* __restrict__ t_w, const float* __restrict__ t_b,
                            float* __restrict__ condG) {
    int g = blockIdx.x;
    int k = threadIdx.x;
    __shared__ float zr[128];
    __shared__ float te[64];
    zr[k] = z[g * 128 + k];
    if (k < 32) {
        float f = __expf(-9.2103403719761836f * (float)k / 31.0f);
        float e = t[g] * f;
        te[k] = sinf(e);
        te[32 + k] = cosf(e);
    }
    __syncthreads();
    float acc = z_b[k] + t_b[k];
    #pragma unroll 8
    for (int i = 0; i < 128; ++i) acc += zr[i] * z_w[i * 128 + k];
    #pragma unroll 8
    for (int i = 0; i < 64; ++i) acc += te[i] * t_w[i * 128 + k];
    condG[g * 128 + k] = acc;
}

// s[n,h] = atom_embed[types[n], h] + condG[batch[n], h]
__global__ void init_kernel(const int* __restrict__ types, const float* __restrict__ emb,
                            const float* __restrict__ condG, const int* __restrict__ batch,
                            float* __restrict__ s, int N_) {
    int i = blockIdx.x * blockDim.x + threadIdx.x;
    if (i < N_ * HD) {
        int n = i >> 7;
        int k = i & 127;
        s[i] = emb[types[n] * HD + k] + condG[batch[n] * 128 + k];
    }
}

__global__ void geom_kernel(const float* __restrict__ coords, const int* __restrict__ srcI,
                            const int* __restrict__ dstI, const int* __restrict__ batch,
                            const float* __restrict__ lattice, const float* __restrict__ offs,
                            float* __restrict__ dist, float* __restrict__ unit, int E_) {
    int e = blockIdx.x * blockDim.x + threadIdx.x;
    if (e >= E_) return;
    int sn = srcI[e], dn = dstI[e];
    float f0 = coords[dn * 3 + 0] - coords[sn * 3 + 0] + offs[e * 3 + 0];
    float f1 = coords[dn * 3 + 1] - coords[sn * 3 + 1] + offs[e * 3 + 1];
    float f2 = coords[dn * 3 + 2] - coords[sn * 3 + 2] + offs[e * 3 + 2];
    const float* Lg = lattice + batch[sn] * 9;
    float c0 = f0 * Lg[0] + f1 * Lg[3] + f2 * Lg[6];
    float c1 = f0 * Lg[1] + f1 * Lg[4] + f2 * Lg[7];
    float c2 = f0 * Lg[2] + f1 * Lg[5] + f2 * Lg[8];
    float nrm = sqrtf(c0 * c0 + c1 * c1 + c2 * c2);
    dist[e] = fmaxf(nrm, 1e-8f);
    float inv = 1.0f / fmaxf(nrm, 1e-12f);
    unit[e * 3 + 0] = c0 * inv;
    unit[e * 3 + 1] = c1 * inv;
    unit[e * 3 + 2] = c2 * inv;
}

__global__ void hist_kernel(const int* __restrict__ dstI, int* __restrict__ cnt, int E_) {
    int e = blockIdx.x * blockDim.x + threadIdx.x;
    if (e < E_) atomicAdd(&cnt[dstI[e]], 1);
}

__global__ __launch_bounds__(1024) void scan_kernel(const int* __restrict__ cnt, int* __restrict__ cur, int n) {
    __shared__ int tmp[1024];
    __shared__ int carry_s;
    if (threadIdx.x == 0) carry_s = 0;
    __syncthreads();
    for (int base = 0; base < n; base += 1024) {
        int i = base + threadIdx.x;
        int x = (i < n) ? cnt[i] : 0;
        tmp[threadIdx.x] = x;
        __syncthreads();
        for (int off = 1; off < 1024; off <<= 1) {
            int y = (threadIdx.x >= off) ? tmp[threadIdx.x - off] : 0;
            __syncthreads();
            tmp[threadIdx.x] += y;
            __syncthreads();
        }
        if (i < n) cur[i] = carry_s + tmp[threadIdx.x] - x;
        __syncthreads();
        if (threadIdx.x == 0) carry_s += tmp[1023];
        __syncthreads();
    }
}

// scatter edges into dst-sorted order; unit packed as float4 (ux,uy,uz,dist)
__global__ void scatter_kernel(const int* __restrict__ srcI, const int* __restrict__ dstI,
                               const float* __restrict__ dist, const float* __restrict__ unit,
                               int* __restrict__ cur,
                               float* __restrict__ dist_s, float4* __restrict__ unit4_s,
                               int* __restrict__ src_s, int* __restrict__ dst_s, int E_) {
    int e = blockIdx.x * blockDim.x + threadIdx.x;
    if (e >= E_) return;
    int d = dstI[e];
    int p = atomicAdd(&cur[d], 1);
    float dd = dist[e];
    dist_s[p] = dd;
    unit4_s[p] = make_float4(unit[e * 3 + 0], unit[e * 3 + 1], unit[e * 3 + 2], dd);
    src_s[p] = srcI[e];
    dst_s[p] = d;
}

// ---- MFMA phi: phi = silu(s@w1+b1)@w2+b2, 32 nodes/block, 256 threads.  phi stored bf16. ----
#define PSA 136
__global__ __launch_bounds__(256, 2) void phi_mfma(
    const float* __restrict__ s,
    const unsigned short* __restrict__ w1h, const unsigned short* __restrict__ w1l,
    const float* __restrict__ b1,
    const unsigned short* __restrict__ w2h, const unsigned short* __restrict__ w2l,
    const float* __restrict__ b2,
    unsigned short* __restrict__ phi, int N_) {
    __shared__ unsigned short Ah[32 * PSA], Al[32 * PSA], Hh[32 * PSA], Hl[32 * PSA];
    const int tid = threadIdx.x;
    const int n0 = blockIdx.x * 32;
    for (int idx = tid; idx < 32 * 128; idx += 256) {
        int j = idx >> 7, k = idx & 127;
        int n = n0 + j; if (n >= N_) n = N_ - 1;
        float x = s[(size_t)n * 128 + k];
        unsigned short h = f2bf(x);
        Ah[j * PSA + k] = h;
        Al[j * PSA + k] = f2bf(x - bf2f(h));
    }
    __syncthreads();
    const int w = tid >> 6, l = tid & 63;
    const int lr = l & 15, lk = (l >> 4) << 3, rg0 = (l >> 4) << 2;
    const f32x4 zero4 = {0.0f, 0.0f, 0.0f, 0.0f};
    f32x4 acc1[2][2];
    #pragma unroll
    for (int rt = 0; rt < 2; ++rt)
        #pragma unroll
        for (int ci = 0; ci < 2; ++ci) acc1[rt][ci] = zero4;
    #pragma unroll
    for (int kt = 0; kt < 4; ++kt) {
        int kk = kt * 32 + lk;
        us8 bh[2], bl[2], ah[2], alo[2];
        #pragma unroll
        for (int ci = 0; ci < 2; ++ci) {
            int col = (w * 2 + ci) * 16 + lr;
            bh[ci] = *(const us8*)(w1h + (size_t)col * 128 + kk);
            bl[ci] = *(const us8*)(w1l + (size_t)col * 128 + kk);
        }
        #pragma unroll
        for (int rt = 0; rt < 2; ++rt) {
            ah[rt]  = *(const us8*)(Ah + (rt * 16 + lr) * PSA + kk);
            alo[rt] = *(const us8*)(Al + (rt * 16 + lr) * PSA + kk);
        }
        #pragma unroll
        for (int rt = 0; rt < 2; ++rt)
            #pragma unroll
            for (int ci = 0; ci < 2; ++ci)
                acc1[rt][ci] = mfma3(ah[rt], alo[rt], bh[ci], bl[ci], acc1[rt][ci]);
    }
    #pragma unroll
    for (int rt = 0; rt < 2; ++rt)
        #pragma unroll
        for (int ci = 0; ci < 2; ++ci) {
            int col = (w * 2 + ci) * 16 + lr;
            float bb = b1[col];
            #pragma unroll
            for (int rg = 0; rg < 4; ++rg) {
                int j = rt * 16 + rg0 + rg;
                float hv = silu_f(acc1[rt][ci][rg] + bb);
                unsigned short hh = f2bf(hv);
                Hh[j * PSA + col] = hh;
                Hl[j * PSA + col] = f2bf(hv - bf2f(hh));
            }
        }
    __syncthreads();
    f32x4 acc2[2][6];
    #pragma unroll
    for (int rt = 0; rt < 2; ++rt)
        #pragma unroll
        for (int ci = 0; ci < 6; ++ci) acc2[rt][ci] = zero4;
    #pragma unroll
    for (int kt = 0; kt < 4; ++kt) {
        int kk = kt * 32 + lk;
        us8 ah[2], alo[2];
        #pragma unroll
        for (int rt = 0; rt < 2; ++rt) {
            ah[rt]  = *(const us8*)(Hh + (rt * 16 + lr) * PSA + kk);
            alo[rt] = *(const us8*)(Hl + (rt * 16 + lr) * PSA + kk);
        }
        #pragma unroll
        for (int ci = 0; ci < 6; ++ci) {
            int col = (w * 6 + ci) * 16 + lr;
            us8 bh = *(const us8*)(w2h + (size_t)col * 128 + kk);
            us8 bl = *(const us8*)(w2l + (size_t)col * 128 + kk);
            #pragma unroll
            for (int rt = 0; rt < 2; ++rt)
                acc2[rt][ci] = mfma3(ah[rt], alo[rt], bh, bl, acc2[rt][ci]);
        }
    }
    #pragma unroll
    for (int rt = 0; rt < 2; ++rt)
        #pragma unroll
        for (int ci = 0; ci < 6; ++ci) {
            int col = (w * 6 + ci) * 16 + lr;
            float bb = b2[col];
            #pragma unroll
            for (int rg = 0; rg < 4; ++rg) {
                int j = rt * 16 + rg0 + rg;
                int n = n0 + j;
                if (n < N_) phi[(size_t)n * 384 + col] = f2bf(acc2[rt][ci][rg] + bb);
            }
        }
}

// ---- MFMA update: 16 nodes/block, 256 threads.  Epilogue also zeroes dv for next layer. ----
__global__ __launch_bounds__(256, 2) void upd_mfma(
    const unsigned short* __restrict__ Uh, const unsigned short* __restrict__ Ul,
    const unsigned short* __restrict__ Vh, const unsigned short* __restrict__ Vl,
    const unsigned short* __restrict__ w1h, const unsigned short* __restrict__ w1l,
    const float* __restrict__ b1,
    const unsigned short* __restrict__ w2h, const unsigned short* __restrict__ w2l,
    const float* __restrict__ b2,
    float* __restrict__ s, float* __restrict__ v, float* __restrict__ dv,
    const float* __restrict__ condG, const int* __restrict__ batch, int addcond, int N_) {
    __shared__ unsigned short SMA[2 * 48 * 136];
    __shared__ float UvL[48 * 132];
    __shared__ float VvL[48 * 132];
    unsigned short* VNh = SMA;
    unsigned short* VNl = SMA + 48 * 136;
    unsigned short* A1h = SMA;
    unsigned short* A1l = SMA + 16 * 264;
    unsigned short* a1h = SMA + 32 * 264;
    unsigned short* a1l = SMA + 32 * 264 + 16 * 136;
    float* o384 = VvL;
    const int tid = threadIdx.x;
    const int n0 = blockIdx.x * 16;
    for (int idx = tid; idx < 48 * 128; idx += 256) {
        int r = idx >> 7, k = idx & 127;
        int c = r >> 4, j = r & 15;
        int n = n0 + j; if (n >= N_) n = N_ - 1;
        size_t off = (size_t)n * 384 + c * 128 + k;
        float x = v[off] + dv[off];
        unsigned short h = f2bf(x);
        VNh[r * 136 + k] = h;
        VNl[r * 136 + k] = f2bf(x - bf2f(h));
    }
    __syncthreads();
    const int w = tid >> 6, l = tid & 63;
    const int lr = l & 15, lk = (l >> 4) << 3, rg0 = (l >> 4) << 2;
    const f32x4 zero4 = {0.0f, 0.0f, 0.0f, 0.0f};
    {
        f32x4 acc[3][2];
        #pragma unroll
        for (int rt = 0; rt < 3; ++rt) { acc[rt][0] = zero4; acc[rt][1] = zero4; }
        #pragma unroll
        for (int kt = 0; kt < 4; ++kt) {
            int kk = kt * 32 + lk;
            us8 bh[2], bl[2];
            #pragma unroll
            for (int ci = 0; ci < 2; ++ci) {
                int col = (w * 2 + ci) * 16 + lr;
                bh[ci] = *(const us8*)(Uh + (size_t)col * 128 + kk);
                bl[ci] = *(const us8*)(Ul + (size_t)col * 128 + kk);
            }
            #pragma unroll
            for (int rt = 0; rt < 3; ++rt) {
                us8 ah  = *(const us8*)(VNh + (rt * 16 + lr) * 136 + kk);
                us8 alo = *(const us8*)(VNl + (rt * 16 + lr) * 136 + kk);
                #pragma unroll
                for (int ci = 0; ci < 2; ++ci)
                    acc[rt][ci] = mfma3(ah, alo, bh[ci], bl[ci], acc[rt][ci]);
            }
        }
        #pragma unroll
        for (int rt = 0; rt < 3; ++rt)
            #pragma unroll
            for (int ci = 0; ci < 2; ++ci) {
                int col = (w * 2 + ci) * 16 + lr;
                #pragma unroll
                for (int rg = 0; rg < 4; ++rg)
                    UvL[(rt * 16 + rg0 + rg) * 132 + col] = acc[rt][ci][rg];
            }
        #pragma unroll
        for (int rt = 0; rt < 3; ++rt) { acc[rt][0] = zero4; acc[rt][1] = zero4; }
        #pragma unroll
        for (int kt = 0; kt < 4; ++kt) {
            int kk = kt * 32 + lk;
            us8 bh[2], bl[2];
            #pragma unroll
            for (int ci = 0; ci < 2; ++ci) {
                int col = (w * 2 + ci) * 16 + lr;
                bh[ci] = *(const us8*)(Vh + (size_t)col * 128 + kk);
                bl[ci] = *(const us8*)(Vl + (size_t)col * 128 + kk);
            }
            #pragma unroll
            for (int rt = 0; rt < 3; ++rt) {
                us8 ah  = *(const us8*)(VNh + (rt * 16 + lr) * 136 + kk);
                us8 alo = *(const us8*)(VNl + (rt * 16 + lr) * 136 + kk);
                #pragma unroll
                for (int ci = 0; ci < 2; ++ci)
                    acc[rt][ci] = mfma3(ah, alo, bh[ci], bl[ci], acc[rt][ci]);
            }
        }
        #pragma unroll
        for (int rt = 0; rt < 3; ++rt)
            #pragma unroll
            for (int ci = 0; ci < 2; ++ci) {
                int col = (w * 2 + ci) * 16 + lr;
                #pragma unroll
                for (int rg = 0; rg < 4; ++rg)
                    VvL[(rt * 16 + rg0 + rg) * 132 + col] = acc[rt][ci][rg];
            }
    }
    __syncthreads();
    float dotr[8];
    {
        int k = tid & 127;
        int jb = (tid >> 7) * 8;
        #pragma unroll
        for (int i = 0; i < 8; ++i) {
            int j = jb + i;
            float uv0 = UvL[j * 132 + k], uv1 = UvL[(16 + j) * 132 + k], uv2 = UvL[(32 + j) * 132 + k];
            float vv0 = VvL[j * 132 + k], vv1 = VvL[(16 + j) * 132 + k], vv2 = VvL[(32 + j) * 132 + k];
            dotr[i] = uv0 * vv0 + uv1 * vv1 + uv2 * vv2;
            float vnv = sqrtf(vv0 * vv0 + vv1 * vv1 + vv2 * vv2 + 1e-8f);
            int n = n0 + j; if (n >= N_) n = N_ - 1;
            float sv = s[(size_t)n * 128 + k];
            unsigned short h1 = f2bf(sv);
            A1h[j * 264 + k] = h1;
            A1l[j * 264 + k] = f2bf(sv - bf2f(h1));
            unsigned short h2 = f2bf(vnv);
            A1h[j * 264 + 128 + k] = h2;
            A1l[j * 264 + 128 + k] = f2bf(vnv - bf2f(h2));
        }
    }
    __syncthreads();
    {
        f32x4 acc[2]; acc[0] = zero4; acc[1] = zero4;
        #pragma unroll
        for (int kt = 0; kt < 8; ++kt) {
            int kk = kt * 32 + lk;
            us8 ah  = *(const us8*)(A1h + lr * 264 + kk);
            us8 alo = *(const us8*)(A1l + lr * 264 + kk);
            #pragma unroll
            for (int ci = 0; ci < 2; ++ci) {
                int col = (w * 2 + ci) * 16 + lr;
                us8 bh = *(const us8*)(w1h + (size_t)col * 256 + kk);
                us8 bl = *(const us8*)(w1l + (size_t)col * 256 + kk);
                acc[ci] = mfma3(ah, alo, bh, bl, acc[ci]);
            }
        }
        #pragma unroll
        for (int ci = 0; ci < 2; ++ci) {
            int col = (w * 2 + ci) * 16 + lr;
            float bb = b1[col];
            #pragma unroll
            for (int rg = 0; rg < 4; ++rg) {
                int j = rg0 + rg;
                float hv = silu_f(acc[ci][rg] + bb);
                unsigned short hh = f2bf(hv);
                a1h[j * 136 + col] = hh;
                a1l[j * 136 + col] = f2bf(hv - bf2f(hh));
            }
        }
    }
    __syncthreads();
    {
        f32x4 acc[6];
        #pragma unroll
        for (int ci = 0; ci < 6; ++ci) acc[ci] = zero4;
        #pragma unroll
        for (int kt = 0; kt < 4; ++kt) {
            int kk = kt * 32 + lk;
            us8 ah  = *(const us8*)(a1h + lr * 136 + kk);
            us8 alo = *(const us8*)(a1l + lr * 136 + kk);
            #pragma unroll
            for (int ci = 0; ci < 6; ++ci) {
                int col = (w * 6 + ci) * 16 + lr;
                us8 bh = *(const us8*)(w2h + (size_t)col * 128 + kk);
                us8 bl = *(const us8*)(w2l + (size_t)col * 128 + kk);
                acc[ci] = mfma3(ah, alo, bh, bl, acc[ci]);
            }
        }
        #pragma unroll
        for (int ci = 0; ci < 6; ++ci) {
            int col = (w * 6 + ci) * 16 + lr;
            float bb = b2[col];
            #pragma unroll
            for (int rg = 0; rg < 4; ++rg) {
                int j = rg0 + rg;
                o384[j * 388 + col] = acc[ci][rg] + bb;
            }
        }
    }
    __syncthreads();
    {
        int k = tid & 127;
        int jb = (tid >> 7) * 8;
        #pragma unroll
        for (int i = 0; i < 8; ++i) {
            int j = jb + i;
            int n = n0 + j;
            if (n >= N_) continue;
            float a0  = o384[j * 388 + k];
            float aH  = o384[j * 388 + 128 + k];
            float a2v = o384[j * 388 + 256 + k];
            #pragma unroll
            for (int c = 0; c < 3; ++c) {
                size_t off = (size_t)n * 384 + c * 128 + k;
                float dvv = dv[off];
                v[off] = v[off] + dvv + a0 * UvL[(c * 16 + j) * 132 + k];
                dv[off] = 0.0f;   // zero for next layer's edge accumulation
            }
            float cadd = addcond ? condG[(size_t)batch[n] * 128 + k] : 0.0f;
            s[(size_t)n * 128 + k] += aH * dotr[i] + a2v + cadd;
        }
    }
}

// ---- MFMA edge v10: round-13 structure, phi gathers in bf16 ----
// 64 sorted edges/block, 256 threads. LDS ~34.8KB -> 4 blocks/CU.
#define EB 64
#define NXCD 8
__global__ __launch_bounds__(256, 4) void edge_mfma(
    const unsigned short* __restrict__ phi, const float* __restrict__ v,
    const float* __restrict__ dist_s, const float4* __restrict__ unit4_s,
    const int* __restrict__ src_s, const int* __restrict__ dst_s,
    const unsigned short* __restrict__ rwh, const unsigned short* __restrict__ rwl,  // [384][64]
    const float* __restrict__ rb,
    float* __restrict__ s, float* __restrict__ dv, int E_, int skipv) {
    __shared__ unsigned short Rh[4096];   // 8192 B  (A frags bf16, persistent)
    __shared__ float filt[16 * 388];      // 24832 B (f32, per-chunk)
    __shared__ int   mSrc[64];            // 256 B
    __shared__ int   mDst[64];            // 256 B
    __shared__ float4 mU4[64];            // 1024 B
    // bijective XCD swizzle (m204)
    int nwg = gridDim.x;
    int q = nwg / NXCD, r = nwg % NXCD;
    int xcd = blockIdx.x % NXCD, bidx = blockIdx.x / NXCD;
    int bid = (xcd < r ? xcd * (q + 1) : r * (q + 1) + (xcd - r) * q) + bidx;
    const int tid = threadIdx.x;
    const int e0 = bid * EB;
    // phase 0: stage the block's 64-edge metadata in LDS (coalesced)
    if (tid < 64) {
        int ec = e0 + tid; if (ec >= E_) ec = E_ - 1;
        mSrc[tid] = src_s[ec];
        mDst[tid] = dst_s[ec];
        mU4[tid]  = unit4_s[ec];
    }
    // phase 1: rbf (bf16) in MFMA A-fragment order:
    // idx = ((kt*4 + mt)*64 + lane)*8 + i -> edge = mt*16+(lane&15), r = kt*32+(lane>>4)*8+i
    #pragma unroll
    for (int it = 0; it < 16; ++it) {
        int idx2 = it * 256 + tid;
        int i = idx2 & 7;
        int l2 = (idx2 >> 3) & 63;
        int mt = (idx2 >> 9) & 3;
        int kt = idx2 >> 11;
        int edge = mt * 16 + (l2 & 15);
        int rr = kt * 32 + ((l2 >> 4) << 3) + i;
        float val = 0.0f;
        int ge = e0 + edge;
        if (ge < E_) {
            float d = dist_s[ge];
            float c = 6.0f * (float)rr / 63.0f;
            float tt = d - c;
            val = __expf(-(64.0f / 6.0f) * tt * tt);
        }
        Rh[idx2] = f2bf(val);
    }
    const int w = tid >> 6, l = tid & 63;
    const int lr = l & 15, rg0 = (l >> 4) << 2;
    const int sub = tid >> 7;        // 0..1
    const int col = tid & 127;
    float bias[6];
    #pragma unroll
    for (int nt = 0; nt < 6; ++nt) bias[nt] = rb[w * 96 + nt * 16 + lr];
    const f32x4 zero4 = {0.0f, 0.0f, 0.0f, 0.0f};
    float as = 0.0f, ad0 = 0.0f, ad1 = 0.0f, ad2 = 0.0f;
    int rd = -1;
    __syncthreads();   // Rh + meta ready
    #pragma unroll
    for (int ch = 0; ch < 4; ++ch) {
        // MFMA for this 16-edge chunk (acc = 24 VGPRs)
        f32x4 acc[6];
        #pragma unroll
        for (int nt = 0; nt < 6; ++nt) acc[nt] = zero4;
        #pragma unroll
        for (int kt = 0; kt < 2; ++kt) {
            int base = ((kt * 4 + ch) * 64 + l) * 8;
            us8 ah = *(const us8*)(Rh + base);
            int kk = kt * 32 + ((l >> 4) << 3);
            #pragma unroll
            for (int nt = 0; nt < 6; ++nt) {
                int c2 = w * 96 + nt * 16 + lr;
                us8 bh = *(const us8*)(rwh + (size_t)c2 * 64 + kk);
                us8 bl = *(const us8*)(rwl + (size_t)c2 * 64 + kk);
                acc[nt] = mfma2(ah, bh, bl, acc[nt]);
            }
        }
        __syncthreads();   // previous chunk's filt fully consumed
        #pragma unroll
        for (int nt = 0; nt < 6; ++nt) {
            int c2 = w * 96 + nt * 16 + lr;
            #pragma unroll
            for (int rg = 0; rg < 4; ++rg)
                filt[(rg0 + rg) * 388 + c2] = acc[nt][rg] + bias[nt];
        }
        __syncthreads();
        // consume: 2 groups of 4 edges; metadata from LDS, gathers prefetched
        int le0 = ch * 16 + sub * 8;
        #pragma unroll
        for (int g = 0; g < 2; ++g) {
            int lb = le0 + g * 4;           // local edge base within block (0..63)
            int sn4[4], dn4[4];
            #pragma unroll
            for (int i = 0; i < 4; ++i) {
                sn4[i] = mSrc[lb + i];
                dn4[i] = mDst[lb + i];
            }
            float P0[4], P1[4], P2[4], V0[4], V1[4], V2[4];
            #pragma unroll
            for (int i = 0; i < 4; ++i) {
                const unsigned short* phr = phi + (size_t)sn4[i] * 384;
                P0[i] = bf2f(phr[col]);
                P1[i] = bf2f(phr[128 + col]);
                P2[i] = bf2f(phr[256 + col]);
            }
            if (!skipv) {
                #pragma unroll
                for (int i = 0; i < 4; ++i) {
                    const float* vr = v + (size_t)sn4[i] * 384;
                    V0[i] = vr[col];
                    V1[i] = vr[128 + col];
                    V2[i] = vr[256 + col];
                }
            } else {
                #pragma unroll
                for (int i = 0; i < 4; ++i) { V0[i] = 0.0f; V1[i] = 0.0f; V2[i] = 0.0f; }
            }
            #pragma unroll
            for (int i = 0; i < 4; ++i) {
                int e = e0 + lb + i;
                if (e >= E_) break;
                int dn = dn4[i];
                if (dn != rd) {   // wave-uniform within sub
                    if (rd >= 0) {
                        atomicAdd(&s[(size_t)rd * 128 + col], as);
                        atomicAdd(&dv[(size_t)rd * 384 + col], ad0);
                        atomicAdd(&dv[(size_t)rd * 384 + 128 + col], ad1);
                        atomicAdd(&dv[(size_t)rd * 384 + 256 + col], ad2);
                    }
                    as = ad0 = ad1 = ad2 = 0.0f;
                    rd = dn;
                }
                int fr = sub * 8 + g * 4 + i;
                float f0 = filt[fr * 388 + col];
                float f1 = filt[fr * 388 + 128 + col];
                float f2v = filt[fr * 388 + 256 + col];
                float x0 = P0[i] * f0;
                float x1 = P1[i] * f1;
                float x2 = P2[i] * f2v;
                float4 u = mU4[lb + i];
                as += x0;
                ad0 += x1 * V0[i] + x2 * u.x;
                ad1 += x1 * V1[i] + x2 * u.y;
                ad2 += x1 * V2[i] + x2 * u.z;
            }
        }
    }
    if (rd >= 0) {
        atomicAdd(&s[(size_t)rd * 128 + col], as);
        atomicAdd(&dv[(size_t)rd * 384 + col], ad0);
        atomicAdd(&dv[(size_t)rd * 384 + 128 + col], ad1);
        atomicAdd(&dv[(size_t)rd * 384 + 256 + col], ad2);
    }
}

// output heads: 8 nodes per block
#define HPB 8
__global__ __launch_bounds__(128, 4) void heads_kernel(
    const float* __restrict__ s,
    const float* __restrict__ hc_w1, const float* __restrict__ hc_b1,
    const float* __restrict__ hc_w2, const float* __restrict__ hc_b2,
    const float* __restrict__ ht_w1, const float* __restrict__ ht_b1,
    const float* __restrict__ ht_w2, const float* __restrict__ ht_b2,
    float* __restrict__ outc, float* __restrict__ outt, int N_) {
    int n0 = blockIdx.x * HPB;
    int k = threadIdx.x;
    __shared__ float sr[HPB][128];
    __shared__ float h1[HPB][128];
    __shared__ float h2[HPB][128];
    #pragma unroll
    for (int j = 0; j < HPB; ++j) {
        int n = n0 + j;
        sr[j][k] = (n < N_) ? s[(size_t)n * 128 + k] : 0.0f;
    }
    __syncthreads();
    float a[HPB], b[HPB];
    #pragma unroll
    for (int j = 0; j < HPB; ++j) { a[j] = hc_b1[k]; b[j] = ht_b1[k]; }
    for (int h = 0; h < 128; h += 4) {
        float wa0 = hc_w1[h * 128 + k],       wa1 = hc_w1[(h + 1) * 128 + k];
        float wa2 = hc_w1[(h + 2) * 128 + k], wa3 = hc_w1[(h + 3) * 128 + k];
        float wb0 = ht_w1[h * 128 + k],       wb1 = ht_w1[(h + 1) * 128 + k];
        float wb2 = ht_w1[(h + 2) * 128 + k], wb3 = ht_w1[(h + 3) * 128 + k];
        #pragma unroll
        for (int j = 0; j < HPB; ++j) {
            const float4 x = *reinterpret_cast<const float4*>(&sr[j][h]);
            a[j] = fmaf(x.w, wa3, fmaf(x.z, wa2, fmaf(x.y, wa1, fmaf(x.x, wa0, a[j]))));
            b[j] = fmaf(x.w, wb3, fmaf(x.z, wb2, fmaf(x.y, wb1, fmaf(x.x, wb0, b[j]))));
        }
    }
    #pragma unroll
    for (int j = 0; j < HPB; ++j) {
        h1[j][k] = silu_f(a[j]);
        h2[j][k] = silu_f(b[j]);
    }
    __syncthreads();
    if (k < 101) {
        for (int j = 0; j < HPB; ++j) {
            int n = n0 + j;
            if (n >= N_) break;
            float c = ht_b2[k];
            #pragma unroll 4
            for (int h = 0; h < 128; ++h) c += h2[j][h] * ht_w2[h * 101 + k];
            outt[(size_t)n * 101 + k] = c;
        }
    }
    if (k < 3) {
        for (int j = 0; j < HPB; ++j) {
            int n = n0 + j;
            if (n >= N_) break;
            float c = hc_b2[k];
            #pragma unroll 4
            for (int h = 0; h < 128; ++h) c += h1[j][h] * hc_w2[h * 3 + k];
            outc[(size_t)n * 3 + k] = c;
        }
    }
}

extern "C" void kernel_launch(void* const* d_in, const int* in_sizes, int n_in,
                              void* d_out, int out_size, void* d_ws, size_t ws_size,
                              hipStream_t stream) {
    const float* coords  = (const float*)d_in[0];
    const int*   types   = (const int*)d_in[1];
    const float* z       = (const float*)d_in[2];
    const float* t       = (const float*)d_in[3];
    const int*   eidx    = (const int*)d_in[4];
    const int*   batch   = (const int*)d_in[5];
    const float* lattice = (const float*)d_in[6];
    const float* offs    = (const float*)d_in[7];
    const float* aemb    = (const float*)d_in[8];
    const float* z_w     = (const float*)d_in[9];
    const float* z_b     = (const float*)d_in[10];
    const float* t_w     = (const float*)d_in[11];
    const float* t_b     = (const float*)d_in[12];
    const float* msg_w1  = (const float*)d_in[13];
    const float* msg_b1  = (const float*)d_in[14];
    const float* msg_w2  = (const float*)d_in[15];
    const float* msg_b2  = (const float*)d_in[16];
    const float* rbf_w   = (const float*)d_in[17];
    const float* rbf_b   = (const float*)d_in[18];
    const float* Um      = (const float*)d_in[19];
    const float* Vm      = (const float*)d_in[20];
    const float* upd_w1  = (const float*)d_in[21];
    const float* upd_b1  = (const float*)d_in[22];
    const float* upd_w2  = (const float*)d_in[23];
    const float* upd_b2  = (const float*)d_in[24];
    const float* hc_w1   = (const float*)d_in[25];
    const float* hc_b1   = (const float*)d_in[26];
    const float* hc_w2   = (const float*)d_in[27];
    const float* hc_b2   = (const float*)d_in[28];
    const float* ht_w1   = (const float*)d_in[29];
    const float* ht_b1   = (const float*)d_in[30];
    const float* ht_w2   = (const float*)d_in[31];
    const float* ht_b2   = (const float*)d_in[32];

    const int N = in_sizes[1];
    const int G = in_sizes[3];
    const int E = in_sizes[4] / 2;
    const int* srcI = eidx;
    const int* dstI = eidx + E;

    char* ws = (char*)d_ws;
    auto alloc = [&](size_t bytes) {
        char* p = ws;
        ws += (bytes + 255) & ~(size_t)255;
        return p;
    };
    float*  s_buf   = (float*)alloc((size_t)N * HD * 4);
    float*  v_buf   = (float*)alloc((size_t)N * H3 * 4);
    float*  dv_buf  = (float*)alloc((size_t)N * H3 * 4);
    unsigned short* phi_buf = (unsigned short*)alloc((size_t)N * H3 * 2);
    float*  condG   = (float*)alloc((size_t)G * HD * 4);
    float*  dist_s  = (float*)alloc((size_t)E * 4);
    float4* unit4_s = (float4*)alloc((size_t)E * 16);
    int*    src_s   = (int*)alloc((size_t)E * 4);
    int*    dst_s   = (int*)alloc((size_t)E * 4);
    int*    cur     = (int*)alloc((size_t)N * 4);
    int*    cnt2    = (int*)alloc((size_t)N * 4);
    float*  dist_t  = (float*)alloc((size_t)E * 4);
    float*  unit_t  = (float*)alloc((size_t)E * 3 * 4);
    // per-layer short offsets inside wpr (layer stride LS = 409600 shorts):
    // pw1 h/l: 0/16384 ; pw2 h/l: 32768/81920 ; uw1 h/l: 131072/163840 ;
    // uw2 h/l: 196608/245760 ; U h/l: 294912/311296 ; V h/l: 327680/344064 ;
    // rw h/l: 360448/385024
    const size_t LS = 409600;
    unsigned short* wpr = (unsigned short*)alloc((size_t)4 * LS * 2);

    hipMemsetAsync(v_buf, 0, (size_t)N * H3 * 4, stream);
    hipMemsetAsync(dv_buf, 0, (size_t)N * H3 * 4, stream);   // layers >0 zeroed by upd_mfma
    hipMemsetAsync(cur, 0, (size_t)N * 4, stream);
    cond_kernel<<<G, 128, 0, stream>>>(z, t, z_w, z_b, t_w, t_b, condG);
    init_kernel<<<(N * HD + 255) / 256, 256, 0, stream>>>(types, aemb, condG, batch, s_buf, N);
    geom_kernel<<<(E + 255) / 256, 256, 0, stream>>>(coords, srcI, dstI, batch, lattice, offs, dist_t, unit_t, E);
    hist_kernel<<<(E + 255) / 256, 256, 0, stream>>>(dstI, cur, E);
    {
        hipMemcpyAsync(cnt2, cur, (size_t)N * 4, hipMemcpyDeviceToDevice, stream);
        scan_kernel<<<1, 1024, 0, stream>>>(cnt2, cur, N);
    }
    scatter_kernel<<<(E + 255) / 256, 256, 0, stream>>>(srcI, dstI, dist_t, unit_t, cur,
                                                        dist_s, unit4_s, src_s, dst_s, E);
    // weight prep (transpose + hi/lo split), 4 layers each
    wprep_kernel<<<256, 256, 0, stream>>>(msg_w1, wpr + 0,      wpr + 16384,  128, 128, 16384, (int)LS, 4);
    wprep_kernel<<<768, 256, 0, stream>>>(msg_w2, wpr + 32768,  wpr + 81920,  128, 384, 49152, (int)LS, 4);
    wprep_kernel<<<512, 256, 0, stream>>>(upd_w1, wpr + 131072, wpr + 163840, 256, 128, 32768, (int)LS, 4);
    wprep_kernel<<<768, 256, 0, stream>>>(upd_w2, wpr + 196608, wpr + 245760, 128, 384, 49152, (int)LS, 4);
    wprep_kernel<<<256, 256, 0, stream>>>(Um,     wpr + 294912, wpr + 311296, 128, 128, 16384, (int)LS, 4);
    wprep_kernel<<<256, 256, 0, stream>>>(Vm,     wpr + 327680, wpr + 344064, 128, 128, 16384, (int)LS, 4);
    wprep_kernel<<<384, 256, 0, stream>>>(rbf_w,  wpr + 360448, wpr + 385024, 64,  384, 24576, (int)LS, 4);

    int eblocks = (E + EB - 1) / EB;
    int pblocks = (N + 31) / 32;
    int ublocks = (N + 15) / 16;
    int hblocks = (N + HPB - 1) / HPB;
    for (int l = 0; l < 4; ++l) {
        const unsigned short* L = wpr + (size_t)l * LS;
        phi_mfma<<<pblocks, 256, 0, stream>>>(s_buf,
                L + 0, L + 16384, msg_b1 + (size_t)l * HD,
                L + 32768, L + 81920, msg_b2 + (size_t)l * H3,
                phi_buf, N);
        edge_mfma<<<eblocks, 256, 0, stream>>>(phi_buf, v_buf, dist_s, unit4_s, src_s, dst_s,
                                               L + 360448, L + 385024,
                                               rbf_b + (size_t)l * H3,
                                               s_buf, dv_buf, E, (l == 0) ? 1 : 0);
        upd_mfma<<<ublocks, 256, 0, stream>>>(
                L + 294912, L + 311296, L + 327680, L + 344064,
                L + 131072, L + 163840, upd_b1 + (size_t)l * HD,
                L + 196608, L + 245760, upd_b2 + (size_t)l * H3,
                s_buf, v_buf, dv_buf, condG, batch, (l < 3) ? 1 : 0, N);
    }
    heads_kernel<<<hblocks, 128, 0, stream>>>(s_buf, hc_w1, hc_b1, hc_w2, hc_b2,
                                        ht_w1, ht_b1, ht_w2, ht_b2,
                                        (float*)d_out, (float*)d_out + (size_t)N * 3, N);
}